// Round 10
// baseline (1416.823 us; speedup 1.0000x reference)
//
#include <hip/hip_runtime.h>
#include <stdint.h>

// LTC encoder B=256,T=1024,F=64,H=128. One WG (512 thr) per batch row.
// R8 post-mortem: critical path was shuffle latency (__shfl -> ds_bpermute ~120cyc
// x ~9 dependent hops) + VGPR cap ~128 (allocator ignores waves_per_eu).
// R9/R10: fused both layers across all 8 waves (80 h2 weight regs/thread - fits cap);
// ALL cross-lane via DPP (quad_perm/row_ror/row_bcast + readlane) - no bpermute;
// 2 barriers/step total; single-buffer packed-f16 h state in LDS.
// R9 bug: LN divisor was 1/512; the ror4/ror8-based reduction counts each of the
// 128 rows exactly ONCE (quads uniform, strided rotation hits each quad once),
// so the correct divisor is 1/128. Fixed here.

#define B_ 256
#define T_ 1024
#define F_ 64
#define H_ 128
#define EPS_ 1e-5f
#define NT_ 512

typedef _Float16 h2 __attribute__((ext_vector_type(2)));
typedef __fp16  f16v2 __attribute__((ext_vector_type(2)));

__device__ __forceinline__ h2 pkf16(float a, float b) {
  union { f16v2 f; h2 h; } c; c.f = __builtin_amdgcn_cvt_pkrtz(a, b); return c.h;
}
__device__ __forceinline__ h2 as_h2(uint32_t u) { union { uint32_t u; h2 h; } c; c.u = u; return c.h; }

#if __has_builtin(__builtin_amdgcn_fdot2)
__device__ __forceinline__ float fdot2(h2 a, h2 b, float c) { return __builtin_amdgcn_fdot2(a, b, c, false); }
#else
__device__ __forceinline__ float fdot2(h2 a, h2 b, float c) { return c + (float)a.x*(float)b.x + (float)a.y*(float)b.y; }
#endif

__device__ __forceinline__ float tanh_fast(float a) {
  float aa = fabsf(a);
  float e  = __expf(2.f * aa);
  float th = 1.f - 2.f / (e + 1.f);
  return copysignf(th, a);
}
__device__ __forceinline__ float softplus_fast(float x) {
  return (x > 20.f) ? x : __logf(1.f + __expf(x));
}

// DPP add: VV_ += dpp_perm(VV_); invalid source lanes contribute 0 (bound_ctrl).
#define DPP_ADD(VV_, CTRL_) { int dt_ = __builtin_amdgcn_update_dpp(0, __float_as_int(VV_), (CTRL_), 0xF, 0xF, true); (VV_) += __int_as_float(dt_); }
// quad K-combine: xor1 (quad_perm [1,0,3,2]=0xB1), xor2 ([2,3,0,1]=0x4E)
#define QSUM(VV_) DPP_ADD(VV_, 0xB1) DPP_ADD(VV_, 0x4E)
// full-wave sum of quad-uniform values: row_ror4+row_ror8 -> each lane = sum of
// its DPP-row's 4 distinct quads (once each); bcast15+bcast31 -> lane 63 = wave
// total (16 distinct rows, once each); readlane broadcasts via SGPR.
#define WRED(VV_) { DPP_ADD(VV_, 0x124) DPP_ADD(VV_, 0x128) DPP_ADD(VV_, 0x142) DPP_ADD(VV_, 0x143) \
  (VV_) = __int_as_float(__builtin_amdgcn_readlane(__float_as_int(VV_), 63)); }

// pack 8 f32->f16 pairs from global, fp32 rows are 4*N4_ floats
#define PACKW(DST_, SRC_, N4_) { const float4* p_ = (const float4*)(SRC_); \
  _Pragma("unroll") \
  for (int ii_ = 0; ii_ < (N4_); ++ii_) { float4 v_ = p_[ii_]; \
    DST_[2*ii_] = pkf16(v_.x, v_.y); DST_[2*ii_+1] = pkf16(v_.z, v_.w); } }

// 16 packed pairs (one K-quarter) from LDS via 4x ds_read_b128
#define LOADHV(HV_, SRC_) { const uint4* p_ = (const uint4*)(SRC_); \
  uint4 a_ = p_[0], b_ = p_[1], c_ = p_[2], d_ = p_[3]; \
  HV_[0]=as_h2(a_.x); HV_[1]=as_h2(a_.y); HV_[2]=as_h2(a_.z); HV_[3]=as_h2(a_.w); \
  HV_[4]=as_h2(b_.x); HV_[5]=as_h2(b_.y); HV_[6]=as_h2(b_.z); HV_[7]=as_h2(b_.w); \
  HV_[8]=as_h2(c_.x); HV_[9]=as_h2(c_.y); HV_[10]=as_h2(c_.z); HV_[11]=as_h2(c_.w); \
  HV_[12]=as_h2(d_.x); HV_[13]=as_h2(d_.y); HV_[14]=as_h2(d_.z); HV_[15]=as_h2(d_.w); }

__global__ void __launch_bounds__(NT_, 2) ltc_scan(
    const float* __restrict__ x,
    const float* __restrict__ Wh0, const float* __restrict__ bh0,
    const float* __restrict__ Wx0, const float* __restrict__ bx0,
    const float* __restrict__ Wt0, const float* __restrict__ bt0,
    const float* __restrict__ tau0, const float* __restrict__ g0,
    const float* __restrict__ be0,
    const float* __restrict__ Wh1, const float* __restrict__ bh1,
    const float* __restrict__ Wx1, const float* __restrict__ bx1,
    const float* __restrict__ Wt1, const float* __restrict__ bt1,
    const float* __restrict__ tau1, const float* __restrict__ g1,
    const float* __restrict__ be1,
    float* __restrict__ out)
{
  __shared__ __align__(16) uint32_t h0p[64];   // h0[t-1], packed f16 pairs (2m,2m+1)
  __shared__ __align__(16) uint32_t h1p[64];   // h1[t-2]
  __shared__ __align__(16) float4   part[8];   // per-wave (s0,s20,s1,s21)

  const int t = threadIdx.x;
  const int q = t & 3;         // K-quarter
  const int j = t >> 2;        // row 0..127 (both layers)
  const int w = t >> 6;        // wave 0..7
  const int l = t & 63;
  const int b = blockIdx.x;

  if (t < 64) { h0p[t] = 0u; h1p[t] = 0u; }

  // ---- register-resident packed-f16 weights: 80 h2 per thread ----
  h2 w0h[16], w0x[8], w0t[8], w1h[16], w1x[16], w1t[16];
  PACKW(w0h, Wh0 + j * H_ + q * 32, 8)
  PACKW(w0x, Wx0 + j * F_ + q * 16, 4)
  PACKW(w0t, Wt0 + j * F_ + q * 16, 4)
  PACKW(w1h, Wh1 + j * H_ + q * 32, 8)
  PACKW(w1x, Wx1 + j * H_ + q * 32, 8)
  PACKW(w1t, Wt1 + j * H_ + q * 32, 8)

  const float bhx0 = bh0[j] + bx0[j];
  const float bt0r = bt0[j], tau0r = tau0[j], g0r = g0[j], be0r = be0[j];
  const float bhx1 = bh1[j] + bx1[j];
  const float bt1r = bt1[j], tau1r = tau1[j], g1r = g1[j], be1r = be1[j];

  // x: this thread's F-quarter (16 floats) per step; prefetch distance 1
  const float4* xq = (const float4*)(x + (size_t)b * (T_ * F_)) + q * 4;
  h2 xv[8];
  { float4 x0 = xq[0], x1 = xq[1], x2 = xq[2], x3 = xq[3];
    xv[0]=pkf16(x0.x,x0.y); xv[1]=pkf16(x0.z,x0.w); xv[2]=pkf16(x1.x,x1.y); xv[3]=pkf16(x1.z,x1.w);
    xv[4]=pkf16(x2.x,x2.y); xv[5]=pkf16(x2.z,x2.w); xv[6]=pkf16(x3.x,x3.y); xv[7]=pkf16(x3.z,x3.w); }

  float hold0 = 0.f, hold1 = 0.f, hnlast = 0.f;
  __syncthreads();

  // iter i: L0 -> h0(i) [i<T], L1 -> h1(i-1) [i>0]
  for (int i = 0; i <= T_; ++i) {
    h2 hv0[16], hv1[16];
    LOADHV(hv0, h0p + q * 16)                  // h0(i-1) (also feeds L1's Wx1/Wt1)
    LOADHV(hv1, h1p + q * 16)                  // h1(i-2)

    float pa0 = 0.f, pb0 = 0.f, pt0v = 0.f, pa1 = 0.f, pb1 = 0.f, pt1v = 0.f;
    #pragma unroll
    for (int ii = 0; ii < 8; ++ii) {
      pa0  = fdot2(w0h[ii],     hv0[ii],     pa0);
      pb0  = fdot2(w0h[8 + ii], hv0[8 + ii], pb0);
      pa1  = fdot2(w1h[ii],     hv1[ii],     pa1);
      pa1  = fdot2(w1h[8 + ii], hv1[8 + ii], pa1);
      pb1  = fdot2(w1x[ii],     hv0[ii],     pb1);
      pb1  = fdot2(w1x[8 + ii], hv0[8 + ii], pb1);
      pt1v = fdot2(w1t[ii],     hv0[ii],     pt1v);
      pt1v = fdot2(w1t[8 + ii], hv0[8 + ii], pt1v);
    }
    #pragma unroll
    for (int ii = 0; ii < 8; ++ii) {
      pb0  = fdot2(w0x[ii], xv[ii], pb0);
      pt0v = fdot2(w0t[ii], xv[ii], pt0v);
    }
    float pA0 = pa0 + pb0, pA1 = pa1 + pb1;

    // prefetch x(i+1) (consumed after barrier1 -> ~400cyc slack)
    int tn = (i < T_ - 1) ? (i + 1) : (T_ - 1);
    const float4* xp = xq + tn * 16;
    float4 xn0 = xp[0], xn1 = xp[1], xn2 = xp[2], xn3 = xp[3];

    // quad K-combine (DPP) -> full dots, quad-uniform
    QSUM(pA0) QSUM(pt0v) QSUM(pA1) QSUM(pt1v)

    // cells
    float f0   = tanh_fast(pA0 + bhx0);
    float tv0  = tau0r + softplus_fast(pt0v + bt0r);
    float hc0  = fmaf(f0 - hold0, __builtin_amdgcn_rcpf(tv0), hold0);
    float f1   = tanh_fast(pA1 + bhx1);
    float tv1  = tau1r + softplus_fast(pt1v + bt1r);
    float hc1  = fmaf(f1 - hold1, __builtin_amdgcn_rcpf(tv1), hold1);

    // LN stats: wave sums (each of the 16 rows counted once)
    float s0 = hc0, s20 = hc0 * hc0, s1 = hc1, s21 = hc1 * hc1;
    WRED(s0) WRED(s20) WRED(s1) WRED(s21)
    if (l == 0) part[w] = make_float4(s0, s20, s1, s21);
    __syncthreads();                           // barrier 1

    float4 v4 = part[q] + part[q + 4];         // 2 broadcast b128 reads
    QSUM(v4.x) QSUM(v4.y) QSUM(v4.z) QSUM(v4.w)

    float mu0 = v4.x * (1.f / 128.f);          // 128 rows, each counted once
    float var0 = v4.y * (1.f / 128.f) - mu0 * mu0;
    float hn0 = fmaf((hc0 - mu0) * rsqrtf(var0 + EPS_), g0r, be0r);
    float mu1 = v4.z * (1.f / 128.f);
    float var1 = v4.w * (1.f / 128.f) - mu1 * mu1;
    float hn1 = fmaf((hc1 - mu1) * rsqrtf(var1 + EPS_), g1r, be1r);

    if (q == 0) ((__fp16*)h0p)[j] = (__fp16)hn0;           // h0(i)
    if (q == 1 && i > 0) ((__fp16*)h1p)[j] = (__fp16)hn1;  // h1(i-1)
    hold0 = hn0;
    if (i > 0) { hold1 = hn1; hnlast = hn1; }

    // repack x for next iter
    xv[0]=pkf16(xn0.x,xn0.y); xv[1]=pkf16(xn0.z,xn0.w); xv[2]=pkf16(xn1.x,xn1.y); xv[3]=pkf16(xn1.z,xn1.w);
    xv[4]=pkf16(xn2.x,xn2.y); xv[5]=pkf16(xn2.z,xn2.w); xv[6]=pkf16(xn3.x,xn3.y); xv[7]=pkf16(xn3.z,xn3.w);
    __syncthreads();                           // barrier 2
  }

  if (q == 0) out[b * H_ + j] = hnlast;        // h1(T-1)
}

extern "C" void kernel_launch(void* const* d_in, const int* in_sizes, int n_in,
                              void* d_out, int out_size, void* d_ws, size_t ws_size,
                              hipStream_t stream) {
  const float* x    = (const float*)d_in[0];
  const float* Wh0  = (const float*)d_in[1];
  const float* bh0  = (const float*)d_in[2];
  const float* Wx0  = (const float*)d_in[3];
  const float* bx0  = (const float*)d_in[4];
  const float* Wt0  = (const float*)d_in[5];
  const float* bt0  = (const float*)d_in[6];
  const float* tau0 = (const float*)d_in[7];
  const float* g0   = (const float*)d_in[8];
  const float* be0  = (const float*)d_in[9];
  const float* Wh1  = (const float*)d_in[10];
  const float* bh1  = (const float*)d_in[11];
  const float* Wx1  = (const float*)d_in[12];
  const float* bx1  = (const float*)d_in[13];
  const float* Wt1  = (const float*)d_in[14];
  const float* bt1  = (const float*)d_in[15];
  const float* tau1 = (const float*)d_in[16];
  const float* g1   = (const float*)d_in[17];
  const float* be1  = (const float*)d_in[18];
  float* out        = (float*)d_out;

  ltc_scan<<<B_, NT_, 0, stream>>>(x, Wh0, bh0, Wx0, bx0, Wt0, bt0, tau0, g0, be0,
                                   Wh1, bh1, Wx1, bx1, Wt1, bt1, tau1, g1, be1, out);
}

// Round 11
// 1361.278 us; speedup vs baseline: 1.0408x; 1.0408x over previous
//
#include <hip/hip_runtime.h>
#include <stdint.h>

// LTC encoder B=256,T=1024,F=64,H=128. One WG (1024 thr, 16 waves) per batch row.
// R10 post-mortem: VGPR=92 proves allocator sinks weight loads whenever per-thread
// demand > ~100 regs (it treats const-memory loads as rematerializable). R11:
// thread = (layer, row, K-quarter) -> 1024 threads, weights 32-48 h2/thread
// (peak live ~100 regs, fits). L0 waves 0-7 compute layer0 step i; L1 waves 8-15
// compute layer1 step i-1 (1-step skew). DPP-only cross-lane. x staged via LDS
// in 64-step f16 chunks so no global load is in flight at any barrier (vmcnt(0)
// drain before s_barrier had been serializing x latency into every iter).

#define B_ 256
#define T_ 1024
#define F_ 64
#define H_ 128
#define EPS_ 1e-5f
#define NT_ 1024

typedef _Float16 h2 __attribute__((ext_vector_type(2)));
typedef __fp16  f16v2 __attribute__((ext_vector_type(2)));

__device__ __forceinline__ h2 pkf16(float a, float b) {
  union { f16v2 f; h2 h; } c; c.f = __builtin_amdgcn_cvt_pkrtz(a, b); return c.h;
}
__device__ __forceinline__ h2 as_h2(uint32_t u) { union { uint32_t u; h2 h; } c; c.u = u; return c.h; }
__device__ __forceinline__ uint32_t as_u32(h2 h) { union { h2 h; uint32_t u; } c; c.h = h; return c.u; }

#if __has_builtin(__builtin_amdgcn_fdot2)
__device__ __forceinline__ float fdot2(h2 a, h2 b, float c) { return __builtin_amdgcn_fdot2(a, b, c, false); }
#else
__device__ __forceinline__ float fdot2(h2 a, h2 b, float c) { return c + (float)a.x*(float)b.x + (float)a.y*(float)b.y; }
#endif

__device__ __forceinline__ float tanh_fast(float a) {
  float aa = fabsf(a);
  float e  = __expf(2.f * aa);
  float th = 1.f - 2.f / (e + 1.f);
  return copysignf(th, a);
}
__device__ __forceinline__ float softplus_fast(float x) {
  return (x > 20.f) ? x : __logf(1.f + __expf(x));
}

// DPP add: VV_ += dpp_perm(VV_); invalid source lanes contribute 0 (bound_ctrl).
#define DPP_ADD(VV_, CTRL_) { int dt_ = __builtin_amdgcn_update_dpp(0, __float_as_int(VV_), (CTRL_), 0xF, 0xF, true); (VV_) += __int_as_float(dt_); }
// quad K-combine: xor1 (quad_perm [1,0,3,2]=0xB1), xor2 ([2,3,0,1]=0x4E)
#define QSUM(VV_) DPP_ADD(VV_, 0xB1) DPP_ADD(VV_, 0x4E)
// full-wave sum of quad-uniform values (16 rows counted once): row_ror4+row_ror8,
// bcast15+bcast31 -> lane 63 total; readlane broadcasts. (verified in R10)
#define WRED(VV_) { DPP_ADD(VV_, 0x124) DPP_ADD(VV_, 0x128) DPP_ADD(VV_, 0x142) DPP_ADD(VV_, 0x143) \
  (VV_) = __int_as_float(__builtin_amdgcn_readlane(__float_as_int(VV_), 63)); }

// pack f32 -> f16 pairs from global; N4_ float4 per row segment
#define PACKW(DST_, SRC_, N4_) { const float4* p_ = (const float4*)(SRC_); \
  _Pragma("unroll") \
  for (int ii_ = 0; ii_ < (N4_); ++ii_) { float4 v_ = p_[ii_]; \
    DST_[2*ii_] = pkf16(v_.x, v_.y); DST_[2*ii_+1] = pkf16(v_.z, v_.w); } }

// 16 packed pairs (one K-quarter, 32 values) from LDS via 4x ds_read_b128
#define LOADHV(HV_, SRC_) { const uint4* p_ = (const uint4*)(SRC_); \
  uint4 a_ = p_[0], b_ = p_[1], c_ = p_[2], d_ = p_[3]; \
  HV_[0]=as_h2(a_.x); HV_[1]=as_h2(a_.y); HV_[2]=as_h2(a_.z); HV_[3]=as_h2(a_.w); \
  HV_[4]=as_h2(b_.x); HV_[5]=as_h2(b_.y); HV_[6]=as_h2(b_.z); HV_[7]=as_h2(b_.w); \
  HV_[8]=as_h2(c_.x); HV_[9]=as_h2(c_.y); HV_[10]=as_h2(c_.z); HV_[11]=as_h2(c_.w); \
  HV_[12]=as_h2(d_.x); HV_[13]=as_h2(d_.y); HV_[14]=as_h2(d_.z); HV_[15]=as_h2(d_.w); }

__global__ void __launch_bounds__(NT_, 4) ltc_scan(
    const float* __restrict__ x,
    const float* __restrict__ Wh0, const float* __restrict__ bh0,
    const float* __restrict__ Wx0, const float* __restrict__ bx0,
    const float* __restrict__ Wt0, const float* __restrict__ bt0,
    const float* __restrict__ tau0, const float* __restrict__ g0,
    const float* __restrict__ be0,
    const float* __restrict__ Wh1, const float* __restrict__ bh1,
    const float* __restrict__ Wx1, const float* __restrict__ bx1,
    const float* __restrict__ Wt1, const float* __restrict__ bt1,
    const float* __restrict__ tau1, const float* __restrict__ g1,
    const float* __restrict__ be1,
    float* __restrict__ out)
{
  __shared__ __align__(16) uint32_t xs[2][2048];   // x chunks: 64 steps x 32 dwords (f16 pairs)
  __shared__ __align__(16) uint32_t h0p[64];       // h0(i-1) packed f16 pairs
  __shared__ __align__(16) uint32_t h1p[64];       // h1(i-2) packed
  __shared__ __align__(16) float2   part[16];      // per-wave (s, s2)

  const int t     = threadIdx.x;
  const int q     = t & 3;          // K-quarter
  const int j     = (t >> 2) & 127; // row
  const int layer = t >> 9;         // 0: waves 0-7, 1: waves 8-15
  const int w     = t >> 6;         // wave 0..15
  const int l     = t & 63;
  const int b     = blockIdx.x;

  if (t < 64) { h0p[t] = 0u; h1p[t] = 0u; }

  // ---- register-resident packed-f16 weights (L0: 32 h2, L1: 48 h2) ----
  h2 wA[16], wX[16], wT[16];
  if (layer == 0) {
    PACKW(wA, Wh0 + j * H_ + q * 32, 8)
    PACKW(wX, Wx0 + j * F_ + q * 16, 4)
    PACKW(wT, Wt0 + j * F_ + q * 16, 4)
  } else {
    PACKW(wA, Wh1 + j * H_ + q * 32, 8)
    PACKW(wX, Wx1 + j * H_ + q * 32, 8)
    PACKW(wT, Wt1 + j * H_ + q * 32, 8)
  }
  const float bhx  = layer ? (bh1[j] + bx1[j]) : (bh0[j] + bx0[j]);
  const float btr  = layer ? bt1[j]  : bt0[j];
  const float taub = layer ? tau1[j] : tau0[j];
  const float gr   = layer ? g1[j]   : g0[j];
  const float ber  = layer ? be1[j]  : be0[j];

  // ---- stage x chunk 0 (f32 -> packed f16): 1 float4 per thread ----
  const float4* xg4 = (const float4*)(x + (size_t)b * (T_ * F_));
  {
    float4 v = xg4[t];
    uint32_t d0 = as_u32(pkf16(v.x, v.y)), d1 = as_u32(pkf16(v.z, v.w));
    *(uint2*)&xs[0][(t >> 4) * 32 + (t & 15) * 2] = make_uint2(d0, d1);
  }
  float hold = 0.f;
  __syncthreads();

  // iter i: L0 threads -> h0(i), L1 threads -> h1(i-1)
  for (int i = 0; i <= T_; ++i) {
    // stage next chunk (uniform branch; load+pack+write inline, once per 64 iters)
    if ((i & 63) == 0) {
      int c = (i >> 6) + 1;
      if (c < 16) {
        float4 v = xg4[c * 1024 + t];
        uint32_t d0 = as_u32(pkf16(v.x, v.y)), d1 = as_u32(pkf16(v.z, v.w));
        *(uint2*)&xs[c & 1][(t >> 4) * 32 + (t & 15) * 2] = make_uint2(d0, d1);
      }
    }

    float pA = 0.f, pT = 0.f;
    if (layer == 0) {
      h2 hv[16];
      LOADHV(hv, h0p + q * 16)                              // h0(i-1)
      const uint4* xr = (const uint4*)&xs[(i >> 6) & 1][(i & 63) * 32 + q * 8];
      uint4 xa = xr[0], xb = xr[1];
      h2 xv[8] = { as_h2(xa.x), as_h2(xa.y), as_h2(xa.z), as_h2(xa.w),
                   as_h2(xb.x), as_h2(xb.y), as_h2(xb.z), as_h2(xb.w) };
      #pragma unroll
      for (int ii = 0; ii < 16; ++ii) pA = fdot2(wA[ii], hv[ii], pA);
      #pragma unroll
      for (int ii = 0; ii < 8; ++ii) {
        pA = fdot2(wX[ii], xv[ii], pA);
        pT = fdot2(wT[ii], xv[ii], pT);
      }
    } else {
      h2 hv[16], hg[16];
      LOADHV(hv, h1p + q * 16)                              // h1(i-2)
      LOADHV(hg, h0p + q * 16)                              // h0(i-1)
      #pragma unroll
      for (int ii = 0; ii < 16; ++ii) {
        pA = fdot2(wA[ii], hv[ii], pA);
        pA = fdot2(wX[ii], hg[ii], pA);
        pT = fdot2(wT[ii], hg[ii], pT);
      }
    }

    QSUM(pA) QSUM(pT)                                        // quad-uniform full dots

    float f  = tanh_fast(pA + bhx);
    float tv = taub + softplus_fast(pT + btr);
    float hc = fmaf(f - hold, __builtin_amdgcn_rcpf(tv), hold);

    float s = hc, s2 = hc * hc;
    WRED(s) WRED(s2)
    if (l == 0) part[w] = make_float2(s, s2);
    __syncthreads();                                         // barrier 1

    const float4* pf = (const float4*)(part + layer * 8);    // my layer's 8 wave-sums
    float4 p0 = pf[0], p1 = pf[1], p2 = pf[2], p3 = pf[3];
    float S  = p0.x + p0.z + p1.x + p1.z + p2.x + p2.z + p3.x + p3.z;
    float S2 = p0.y + p0.w + p1.y + p1.w + p2.y + p2.w + p3.y + p3.w;
    float mu  = S * (1.f / 128.f);
    float var = S2 * (1.f / 128.f) - mu * mu;
    float hn  = fmaf((hc - mu) * rsqrtf(var + EPS_), gr, ber);

    bool valid = (layer == 0) || (i > 0);
    if (valid && q == 0) ((__fp16*)(layer ? h1p : h0p))[j] = (__fp16)hn;
    if (valid) hold = hn;
    __syncthreads();                                         // barrier 2
  }

  if (layer == 1 && q == 0) out[b * H_ + j] = hold;          // h1(T-1)
}

extern "C" void kernel_launch(void* const* d_in, const int* in_sizes, int n_in,
                              void* d_out, int out_size, void* d_ws, size_t ws_size,
                              hipStream_t stream) {
  const float* x    = (const float*)d_in[0];
  const float* Wh0  = (const float*)d_in[1];
  const float* bh0  = (const float*)d_in[2];
  const float* Wx0  = (const float*)d_in[3];
  const float* bx0  = (const float*)d_in[4];
  const float* Wt0  = (const float*)d_in[5];
  const float* bt0  = (const float*)d_in[6];
  const float* tau0 = (const float*)d_in[7];
  const float* g0   = (const float*)d_in[8];
  const float* be0  = (const float*)d_in[9];
  const float* Wh1  = (const float*)d_in[10];
  const float* bh1  = (const float*)d_in[11];
  const float* Wx1  = (const float*)d_in[12];
  const float* bx1  = (const float*)d_in[13];
  const float* Wt1  = (const float*)d_in[14];
  const float* bt1  = (const float*)d_in[15];
  const float* tau1 = (const float*)d_in[16];
  const float* g1   = (const float*)d_in[17];
  const float* be1  = (const float*)d_in[18];
  float* out        = (float*)d_out;

  ltc_scan<<<B_, NT_, 0, stream>>>(x, Wh0, bh0, Wx0, bx0, Wt0, bt0, tau0, g0, be0,
                                   Wh1, bh1, Wx1, bx1, Wt1, bt1, tau1, g1, be1, out);
}

// Round 12
// 1354.721 us; speedup vs baseline: 1.0458x; 1.0048x over previous
//
#include <hip/hip_runtime.h>
#include <stdint.h>

// LTC encoder B=256,T=1024,F=64,H=128. One WG (1024 thr, 16 waves) per batch row.
// R11 post-mortem: VGPR=56 at ~95-reg demand proves LLVM *rematerializes/sinks*
// read-only-global weight loads into the loop regardless of budget -> every round
// so far was L2-BW-bound on 327KB/CU/iter weight re-fetch (3000 cyc/iter model
// matches 3180 measured). R12 = R11 + non-remat weight defs: each packed weight
// word is the OUTPUT of asm volatile("" : "+v") -> cannot be re-executed or sunk;
// demand ~95 regs < 128 budget (R6's pin failed because its demand was 192+).

#define B_ 256
#define T_ 1024
#define F_ 64
#define H_ 128
#define EPS_ 1e-5f
#define NT_ 1024

typedef _Float16 h2 __attribute__((ext_vector_type(2)));
typedef __fp16  f16v2 __attribute__((ext_vector_type(2)));

__device__ __forceinline__ h2 pkf16(float a, float b) {
  union { f16v2 f; h2 h; } c; c.f = __builtin_amdgcn_cvt_pkrtz(a, b); return c.h;
}
__device__ __forceinline__ h2 as_h2(uint32_t u) { union { uint32_t u; h2 h; } c; c.u = u; return c.h; }
__device__ __forceinline__ uint32_t as_u32(h2 h) { union { h2 h; uint32_t u; } c; c.h = h; return c.u; }

#if __has_builtin(__builtin_amdgcn_fdot2)
__device__ __forceinline__ float fdot2(h2 a, h2 b, float c) { return __builtin_amdgcn_fdot2(a, b, c, false); }
#else
__device__ __forceinline__ float fdot2(h2 a, h2 b, float c) { return c + (float)a.x*(float)b.x + (float)a.y*(float)b.y; }
#endif

__device__ __forceinline__ float tanh_fast(float a) {
  float aa = fabsf(a);
  float e  = __expf(2.f * aa);
  float th = 1.f - 2.f / (e + 1.f);
  return copysignf(th, a);
}
__device__ __forceinline__ float softplus_fast(float x) {
  return (x > 20.f) ? x : __logf(1.f + __expf(x));
}

// DPP add: VV_ += dpp_perm(VV_); invalid source lanes contribute 0 (bound_ctrl).
#define DPP_ADD(VV_, CTRL_) { int dt_ = __builtin_amdgcn_update_dpp(0, __float_as_int(VV_), (CTRL_), 0xF, 0xF, true); (VV_) += __int_as_float(dt_); }
// quad K-combine: xor1 (quad_perm [1,0,3,2]=0xB1), xor2 ([2,3,0,1]=0x4E)
#define QSUM(VV_) DPP_ADD(VV_, 0xB1) DPP_ADD(VV_, 0x4E)
// full-wave sum of quad-uniform values (16 rows counted once): row_ror4+row_ror8,
// bcast15+bcast31 -> lane 63 total; readlane broadcasts. (verified R10)
#define WRED(VV_) { DPP_ADD(VV_, 0x124) DPP_ADD(VV_, 0x128) DPP_ADD(VV_, 0x142) DPP_ADD(VV_, 0x143) \
  (VV_) = __int_as_float(__builtin_amdgcn_readlane(__float_as_int(VV_), 63)); }

// pack f32 -> f16 pair words from global; N4_ float4 per row segment
#define PACKW(DST_, SRC_, N4_) { const float4* p_ = (const float4*)(SRC_); \
  _Pragma("unroll") \
  for (int ii_ = 0; ii_ < (N4_); ++ii_) { float4 v_ = p_[ii_]; \
    DST_[2*ii_] = as_u32(pkf16(v_.x, v_.y)); DST_[2*ii_+1] = as_u32(pkf16(v_.z, v_.w)); } }

// non-rematerializable def: value becomes an asm output the compiler can't re-derive
#define PINA(ARR_, N_) { _Pragma("unroll") \
  for (int ii_ = 0; ii_ < (N_); ++ii_) asm volatile("" : "+v"(ARR_[ii_])); }

// 16 packed pairs (one K-quarter, 32 values) from LDS via 4x ds_read_b128
#define LOADHV(HV_, SRC_) { const uint4* p_ = (const uint4*)(SRC_); \
  uint4 a_ = p_[0], b_ = p_[1], c_ = p_[2], d_ = p_[3]; \
  HV_[0]=as_h2(a_.x); HV_[1]=as_h2(a_.y); HV_[2]=as_h2(a_.z); HV_[3]=as_h2(a_.w); \
  HV_[4]=as_h2(b_.x); HV_[5]=as_h2(b_.y); HV_[6]=as_h2(b_.z); HV_[7]=as_h2(b_.w); \
  HV_[8]=as_h2(c_.x); HV_[9]=as_h2(c_.y); HV_[10]=as_h2(c_.z); HV_[11]=as_h2(c_.w); \
  HV_[12]=as_h2(d_.x); HV_[13]=as_h2(d_.y); HV_[14]=as_h2(d_.z); HV_[15]=as_h2(d_.w); }

__global__ void __launch_bounds__(NT_, 4) ltc_scan(
    const float* __restrict__ x,
    const float* __restrict__ Wh0, const float* __restrict__ bh0,
    const float* __restrict__ Wx0, const float* __restrict__ bx0,
    const float* __restrict__ Wt0, const float* __restrict__ bt0,
    const float* __restrict__ tau0, const float* __restrict__ g0,
    const float* __restrict__ be0,
    const float* __restrict__ Wh1, const float* __restrict__ bh1,
    const float* __restrict__ Wx1, const float* __restrict__ bx1,
    const float* __restrict__ Wt1, const float* __restrict__ bt1,
    const float* __restrict__ tau1, const float* __restrict__ g1,
    const float* __restrict__ be1,
    float* __restrict__ out)
{
  __shared__ __align__(16) uint32_t xs[2][2048];   // x chunks: 64 steps x 32 dwords (f16 pairs)
  __shared__ __align__(16) uint32_t h0p[64];       // h0(i-1) packed f16 pairs
  __shared__ __align__(16) uint32_t h1p[64];       // h1(i-2) packed
  __shared__ __align__(16) float2   part[16];      // per-wave (s, s2)

  const int t     = threadIdx.x;
  const int q     = t & 3;          // K-quarter
  const int j     = (t >> 2) & 127; // row
  const int layer = t >> 9;         // 0: waves 0-7, 1: waves 8-15
  const int w     = t >> 6;         // wave 0..15
  const int l     = t & 63;
  const int b     = blockIdx.x;

  if (t < 64) { h0p[t] = 0u; h1p[t] = 0u; }

  // ---- register-resident packed-f16 weights (L0: 32 words, L1: 48 words) ----
  uint32_t wA[16], wX[16], wT[16];
  if (layer == 0) {
    PACKW(wA, Wh0 + j * H_ + q * 32, 8)
    PACKW(wX, Wx0 + j * F_ + q * 16, 4)
    PACKW(wT, Wt0 + j * F_ + q * 16, 4)
    #pragma unroll
    for (int ii = 8; ii < 16; ++ii) { wX[ii] = 0u; wT[ii] = 0u; }
  } else {
    PACKW(wA, Wh1 + j * H_ + q * 32, 8)
    PACKW(wX, Wx1 + j * H_ + q * 32, 8)
    PACKW(wT, Wt1 + j * H_ + q * 32, 8)
  }
  PINA(wA, 16) PINA(wX, 16) PINA(wT, 16)

  const float bhx  = layer ? (bh1[j] + bx1[j]) : (bh0[j] + bx0[j]);
  const float btr  = layer ? bt1[j]  : bt0[j];
  const float taub = layer ? tau1[j] : tau0[j];
  const float gr   = layer ? g1[j]   : g0[j];
  const float ber  = layer ? be1[j]  : be0[j];

  // ---- stage x chunk 0 (f32 -> packed f16): 1 float4 per thread ----
  const float4* xg4 = (const float4*)(x + (size_t)b * (T_ * F_));
  {
    float4 v = xg4[t];
    uint32_t d0 = as_u32(pkf16(v.x, v.y)), d1 = as_u32(pkf16(v.z, v.w));
    *(uint2*)&xs[0][(t >> 4) * 32 + (t & 15) * 2] = make_uint2(d0, d1);
  }
  float hold = 0.f;
  __syncthreads();

  // iter i: L0 threads -> h0(i), L1 threads -> h1(i-1)
  for (int i = 0; i <= T_; ++i) {
    // stage next chunk (uniform branch; once per 64 iters)
    if ((i & 63) == 0) {
      int c = (i >> 6) + 1;
      if (c < 16) {
        float4 v = xg4[c * 1024 + t];
        uint32_t d0 = as_u32(pkf16(v.x, v.y)), d1 = as_u32(pkf16(v.z, v.w));
        *(uint2*)&xs[c & 1][(t >> 4) * 32 + (t & 15) * 2] = make_uint2(d0, d1);
      }
    }

    float pA = 0.f, pT = 0.f;
    if (layer == 0) {
      h2 hv[16];
      LOADHV(hv, h0p + q * 16)                              // h0(i-1)
      const uint4* xr = (const uint4*)&xs[(i >> 6) & 1][(i & 63) * 32 + q * 8];
      uint4 xa = xr[0], xb = xr[1];
      h2 xv[8] = { as_h2(xa.x), as_h2(xa.y), as_h2(xa.z), as_h2(xa.w),
                   as_h2(xb.x), as_h2(xb.y), as_h2(xb.z), as_h2(xb.w) };
      #pragma unroll
      for (int ii = 0; ii < 16; ++ii) pA = fdot2(as_h2(wA[ii]), hv[ii], pA);
      #pragma unroll
      for (int ii = 0; ii < 8; ++ii) {
        pA = fdot2(as_h2(wX[ii]), xv[ii], pA);
        pT = fdot2(as_h2(wT[ii]), xv[ii], pT);
      }
    } else {
      h2 hv[16], hg[16];
      LOADHV(hv, h1p + q * 16)                              // h1(i-2)
      LOADHV(hg, h0p + q * 16)                              // h0(i-1)
      #pragma unroll
      for (int ii = 0; ii < 16; ++ii) {
        pA = fdot2(as_h2(wA[ii]), hv[ii], pA);
        pA = fdot2(as_h2(wX[ii]), hg[ii], pA);
        pT = fdot2(as_h2(wT[ii]), hg[ii], pT);
      }
    }

    QSUM(pA) QSUM(pT)                                        // quad-uniform full dots

    float f  = tanh_fast(pA + bhx);
    float tv = taub + softplus_fast(pT + btr);
    float hc = fmaf(f - hold, __builtin_amdgcn_rcpf(tv), hold);

    float s = hc, s2 = hc * hc;
    WRED(s) WRED(s2)
    if (l == 0) part[w] = make_float2(s, s2);
    __syncthreads();                                         // barrier 1

    const float4* pf = (const float4*)(part + layer * 8);    // my layer's 8 wave-sums
    float4 p0 = pf[0], p1 = pf[1], p2 = pf[2], p3 = pf[3];
    float S  = p0.x + p0.z + p1.x + p1.z + p2.x + p2.z + p3.x + p3.z;
    float S2 = p0.y + p0.w + p1.y + p1.w + p2.y + p2.w + p3.y + p3.w;
    float mu  = S * (1.f / 128.f);
    float var = S2 * (1.f / 128.f) - mu * mu;
    float hn  = fmaf((hc - mu) * rsqrtf(var + EPS_), gr, ber);

    bool valid = (layer == 0) || (i > 0);
    if (valid && q == 0) ((__fp16*)(layer ? h1p : h0p))[j] = (__fp16)hn;
    if (valid) hold = hn;
    __syncthreads();                                         // barrier 2
  }

  if (layer == 1 && q == 0) out[b * H_ + j] = hold;          // h1(T-1)
}

extern "C" void kernel_launch(void* const* d_in, const int* in_sizes, int n_in,
                              void* d_out, int out_size, void* d_ws, size_t ws_size,
                              hipStream_t stream) {
  const float* x    = (const float*)d_in[0];
  const float* Wh0  = (const float*)d_in[1];
  const float* bh0  = (const float*)d_in[2];
  const float* Wx0  = (const float*)d_in[3];
  const float* bx0  = (const float*)d_in[4];
  const float* Wt0  = (const float*)d_in[5];
  const float* bt0  = (const float*)d_in[6];
  const float* tau0 = (const float*)d_in[7];
  const float* g0   = (const float*)d_in[8];
  const float* be0  = (const float*)d_in[9];
  const float* Wh1  = (const float*)d_in[10];
  const float* bh1  = (const float*)d_in[11];
  const float* Wx1  = (const float*)d_in[12];
  const float* bx1  = (const float*)d_in[13];
  const float* Wt1  = (const float*)d_in[14];
  const float* bt1  = (const float*)d_in[15];
  const float* tau1 = (const float*)d_in[16];
  const float* g1   = (const float*)d_in[17];
  const float* be1  = (const float*)d_in[18];
  float* out        = (float*)d_out;

  ltc_scan<<<B_, NT_, 0, stream>>>(x, Wh0, bh0, Wx0, bx0, Wt0, bt0, tau0, g0, be0,
                                   Wh1, bh1, Wx1, bx1, Wt1, bt1, tau1, g1, be1, out);
}